// Round 7
// baseline (225.961 us; speedup 1.0000x reference)
//
#include <hip/hip_runtime.h>
#include <math.h>

// Problem constants (MoEGate: B=4,T=4096,C=2048,E=64,K=8)
#define NTOK   16384
#define CDIM   2048
#define NEXP   64
#define TOPK   8
#define TOKB   32            // tokens per block (2 MFMA row-tiles)
#define NWAVE  8             // waves per block (in-block k-split factor)
#define GBLK   (NTOK / TOKB) // 512 blocks
#define XPITCH 1040          // LDS row pitch (bytes): 1024 + 16 staggers banks

typedef _Float16 f16x8 __attribute__((ext_vector_type(8)));
typedef float    f32x4 __attribute__((ext_vector_type(4)));

// ============================================================================
// Kernel 1: pack W[64][2048] fp32 into f16 hi/lo images in MFMA B-fragment
// order. Entry t = ((s*4 + nt)*64 + lane): 8 f16 for (expert = nt*16+(lane&15),
// k = s*32 + (lane>>4)*8 + j). GEMM lane then loads one contiguous 16B chunk.
// ============================================================================
__global__ __launch_bounds__(256) void pack_w16_kernel(
    const float* __restrict__ W,
    _Float16* __restrict__ Wh, _Float16* __restrict__ Wl)
{
    int t    = blockIdx.x * 256 + threadIdx.x;   // 0..16383
    int lane = t & 63;
    int nt   = (t >> 6) & 3;
    int s    = t >> 8;                           // k32-step, 0..63
    int e    = nt * 16 + (lane & 15);
    int k    = s * 32 + (lane >> 4) * 8;
    const float* src = W + (size_t)e * CDIM + k;
    #pragma unroll
    for (int j = 0; j < 8; j++) {
        float x = src[j];
        _Float16 h = (_Float16)x;                // rte
        Wh[(size_t)t * 8 + j] = h;
        Wl[(size_t)t * 8 + j] = (_Float16)(x - (float)h);
    }
}

__device__ __forceinline__ void split_f16(
    const float4 v0, const float4 v1, f16x8& ah, f16x8& al)
{
    float xr[8] = {v0.x, v0.y, v0.z, v0.w, v1.x, v1.y, v1.z, v1.w};
    #pragma unroll
    for (int j = 0; j < 8; j++) {
        _Float16 h = (_Float16)xr[j];
        ah[j] = h;
        al[j] = (_Float16)(xr[j] - (float)h);    // exact residual
    }
}

// ============================================================================
// Kernel 2 (FUSED): reg-staged LDS streaming + raw-barrier counted-vmcnt
// pipeline (T3/T4 minimum form) + 8-way k-split.
// R14: R13's global_load_lds regressed (gate 124us, LDS conflicts 3.9K->528K
// from the DMA writes to pitched rows) AND its pipelining was void:
// __syncthreads() always drains vmcnt(0) before s_barrier, so stage(c+1)
// could never stay in flight. Revert to R12's reg-staged path (best known,
// <77us) and replace sync with: asm lgkmcnt(0) + RAW s_barrier (no vmcnt
// drain). Per chunk: ds_write v(c); publish(lgkm0+bar); issue 8 W loads
// (OLDER) then 4 v(c+1) loads (NEWER); ds_read A-frags; split; MFMA —
// compiler's static vmcnt bookkeeping waits only the W's (vmcnt(4)),
// leaving v(c+1) in flight across the consume phase AND the bottom raw
// barrier; next iter's ds_write waits vmcnt(0) = just those 4 loads, now
// ~400cy old. sched_barrier(0) pins regions (rule #18 hoist hazard).
// Reads complete (compiler lgkm wait) before each wave's split, hence
// before the bottom barrier => buffer reuse is race-free. LDS x-buffer
// (33 KB, 1040-B pitch = 2-way alias, free) aliases the dead 64-KB sacc.
// 2 blocks/CU, grid 512, (512,4). Epilogue unchanged (verified): waves 0/1
// reduce w-ascending + 16-lane shfl_xor top-8 (strict >, lowest index wins
// ties = JAX). ZERO global atomics.
// ============================================================================
__global__ __launch_bounds__(512, 4) void gate_fused_kernel(
    const float* __restrict__ x,       // [NTOK][CDIM]
    const _Float16* __restrict__ Wh,   // packed image, 256 KB (L2-hot)
    const _Float16* __restrict__ Wl,   // packed image, 256 KB (L2-hot)
    const int*   __restrict__ mask,    // [NTOK]
    const float* __restrict__ gbias,   // [NEXP]
    const float* __restrict__ ebias,   // [NEXP]
    float*       __restrict__ out,     // [2*NTOK*TOPK + 1]
    float*       __restrict__ blockcnt)// [GBLK][NEXP]
{
    __shared__ f32x4 sacc[NWAVE][2][4][64];  // 64 KB; first 33280 B alias = x-stage
    __shared__ unsigned int cnt[NEXP];
    char* lds_x = (char*)sacc;               // [32 rows][XPITCH] staging buffer

    const int tid  = threadIdx.x;
    const int lane = tid & 63;
    const int wid  = tid >> 6;               // 0..7
    if (tid < NEXP) cnt[tid] = 0u;

    const int tok0 = blockIdx.x * TOKB;
    const int col  = lane & 15;              // token row for A / expert col for C
    const int q    = lane >> 4;              // quad
    const char* gx = (const char*)(x + (size_t)tok0 * CDIM);
    const f16x8* whp = (const f16x8*)Wh + lane;
    const f16x8* wlp = (const f16x8*)Wl + lane;

    f32x4 accA[4], accB[4];
    #pragma unroll
    for (int nt = 0; nt < 4; nt++) {
        accA[nt] = (f32x4){0.f, 0.f, 0.f, 0.f};
        accB[nt] = (f32x4){0.f, 0.f, 0.f, 0.f};
    }

    const int rowA = col, rowB = 16 + col;
    const unsigned offb = (unsigned)(wid * 128 + q * 32);

    // prologue: chunk 0 x-rows -> registers (4 rows/wave, 1 KB each)
    float4 v0 = *(const float4*)(gx + (size_t)(wid * 4 + 0) * 8192 + lane * 16);
    float4 v1 = *(const float4*)(gx + (size_t)(wid * 4 + 1) * 8192 + lane * 16);
    float4 v2 = *(const float4*)(gx + (size_t)(wid * 4 + 2) * 8192 + lane * 16);
    float4 v3 = *(const float4*)(gx + (size_t)(wid * 4 + 3) * 8192 + lane * 16);

    #pragma unroll
    for (int c = 0; c < 8; c++) {
        // ---- stage-write: v(c) regs -> LDS (compiler waits vmcnt for v) ----
        *(float4*)(lds_x + (wid * 4 + 0) * XPITCH + lane * 16) = v0;
        *(float4*)(lds_x + (wid * 4 + 1) * XPITCH + lane * 16) = v1;
        *(float4*)(lds_x + (wid * 4 + 2) * XPITCH + lane * 16) = v2;
        *(float4*)(lds_x + (wid * 4 + 3) * XPITCH + lane * 16) = v3;
        asm volatile("s_waitcnt lgkmcnt(0)" ::: "memory");  // writes visible
        __builtin_amdgcn_s_barrier();                       // publish (NO vmcnt drain)
        __builtin_amdgcn_sched_barrier(0);

        // ---- issue W(c) loads FIRST (older in vmcnt order) ----
        const int S = c * 8 + wid;           // global k32-step (k-remap, verified)
        f16x8 bh[4], bl[4];
        #pragma unroll
        for (int nt = 0; nt < 4; nt++) {
            bh[nt] = whp[(size_t)S * 256 + nt * 64];
            bl[nt] = wlp[(size_t)S * 256 + nt * 64];
        }
        __builtin_amdgcn_sched_barrier(0);   // keep W older than v(c+1)

        // ---- issue v(c+1) loads (newer; stay in flight across consume+barrier)
        if (c < 7) {
            const char* gc = gx + (size_t)(c + 1) * 1024;
            v0 = *(const float4*)(gc + (size_t)(wid * 4 + 0) * 8192 + lane * 16);
            v1 = *(const float4*)(gc + (size_t)(wid * 4 + 1) * 8192 + lane * 16);
            v2 = *(const float4*)(gc + (size_t)(wid * 4 + 2) * 8192 + lane * 16);
            v3 = *(const float4*)(gc + (size_t)(wid * 4 + 3) * 8192 + lane * 16);
        }
        __builtin_amdgcn_sched_barrier(0);   // v issued before consume section

        // ---- consume: A-frags from LDS (2-way alias, free), split, MFMA ----
        float4 a0 = *(const float4*)(lds_x + rowA * XPITCH + offb);
        float4 a1 = *(const float4*)(lds_x + rowA * XPITCH + offb + 16);
        float4 c0 = *(const float4*)(lds_x + rowB * XPITCH + offb);
        float4 c1 = *(const float4*)(lds_x + rowB * XPITCH + offb + 16);
        f16x8 ahA, alA, ahB, alB;
        split_f16(a0, a1, ahA, alA);         // compiler: lgkm wait before use
        split_f16(c0, c1, ahB, alB);
        #pragma unroll
        for (int nt = 0; nt < 4; nt++) {     // compiler: vmcnt(4) for W (v in flight)
            accA[nt] = __builtin_amdgcn_mfma_f32_16x16x32_f16(ahA, bh[nt], accA[nt], 0, 0, 0);
            accA[nt] = __builtin_amdgcn_mfma_f32_16x16x32_f16(alA, bh[nt], accA[nt], 0, 0, 0);
            accA[nt] = __builtin_amdgcn_mfma_f32_16x16x32_f16(ahA, bl[nt], accA[nt], 0, 0, 0);
            accB[nt] = __builtin_amdgcn_mfma_f32_16x16x32_f16(ahB, bh[nt], accB[nt], 0, 0, 0);
            accB[nt] = __builtin_amdgcn_mfma_f32_16x16x32_f16(alB, bh[nt], accB[nt], 0, 0, 0);
            accB[nt] = __builtin_amdgcn_mfma_f32_16x16x32_f16(ahB, bl[nt], accB[nt], 0, 0, 0);
        }
        __builtin_amdgcn_sched_barrier(0);
        __builtin_amdgcn_s_barrier();        // all waves done reading buffer
        __builtin_amdgcn_sched_barrier(0);
    }

    // Bottom barrier of c=7 guarantees all x-buffer reads done -> sacc safe.
    #pragma unroll
    for (int nt = 0; nt < 4; nt++) {
        sacc[wid][0][nt][lane] = accA[nt];
        sacc[wid][1][nt][lane] = accB[nt];
    }
    __syncthreads();                         // full drain fine here (nothing in flight)

    // ---- epilogue: wave 0 -> tokenset 0, wave 1 -> tokenset 1
    if (wid < 2) {
        const int ts = wid;
        f32x4 zv[4];
        #pragma unroll
        for (int nt = 0; nt < 4; nt++) {
            f32x4 s = sacc[0][ts][nt][lane];
            #pragma unroll
            for (int w = 1; w < NWAVE; w++) s += sacc[w][ts][nt][lane];
            zv[nt] = s;
        }

        float gb[4], eb[4];
        #pragma unroll
        for (int nt = 0; nt < 4; nt++) {
            gb[nt] = gbias[nt * 16 + col];
            eb[nt] = ebias[nt * 16 + col];
        }

        #pragma unroll
        for (int r = 0; r < 4; r++) {
            const int t = tok0 + ts * 16 + q * 4 + r;   // C layout: row = q*4+reg
            float z[4], sel[4];
            #pragma unroll
            for (int nt = 0; nt < 4; nt++) {
                z[nt]   = zv[nt][r] + gb[nt];
                sel[nt] = z[nt] + eb[nt];
            }

            int idxs[TOPK]; float probs[TOPK]; float psum = 0.f;
            #pragma unroll
            for (int rr = 0; rr < TOPK; rr++) {
                float bv = -INFINITY, bz = 0.f; int bidx = 1 << 30;
                #pragma unroll
                for (int nt = 0; nt < 4; nt++)
                    if (sel[nt] > bv) { bv = sel[nt]; bz = z[nt]; bidx = nt * 16 + col; }
                #pragma unroll
                for (int m = 1; m < 16; m <<= 1) {   // xor<16 stays in 16-lane group
                    float ov = __shfl_xor(bv, m);
                    float oz = __shfl_xor(bz, m);
                    int   oi = __shfl_xor(bidx, m);
                    if (ov > bv || (ov == bv && oi < bidx)) { bv = ov; bz = oz; bidx = oi; }
                }
                idxs[rr] = bidx;
                float p = 1.f / (1.f + expf(-bz));
                probs[rr] = p; psum += p;
                if ((bidx & 15) == col) sel[bidx >> 4] = -INFINITY;   // mark used
            }
            float inv = 1.f / psum;
            if (col < TOPK) {
                out[(size_t)t * TOPK + col] = (float)idxs[col];
                out[(size_t)NTOK * TOPK + (size_t)t * TOPK + col] = probs[col] * inv;
                if (mask[t] != 0) atomicAdd(&cnt[idxs[col]], 1u);
            }
        }
    }
    __syncthreads();
    if (tid < NEXP)
        blockcnt[(size_t)blockIdx.x * NEXP + tid] = (float)cnt[tid];
}

// ============================================================================
// Kernel 3: tree-sum per-block counts -> maxvio. One block, 256 threads.
// ============================================================================
__global__ __launch_bounds__(256) void finalize_kernel(
    const float* __restrict__ blockcnt, float* __restrict__ out)
{
    __shared__ float ps[4][NEXP];
    const int t = threadIdx.x;
    const int e = t & 63, c = t >> 6;
    float s = 0.f;
    #pragma unroll 8
    for (int b = 0; b < GBLK / 4; b++)
        s += blockcnt[(size_t)(c * (GBLK / 4) + b) * NEXP + e];
    ps[c][e] = s;
    __syncthreads();
    if (t < 64) {
        float tot = ps[0][t] + ps[1][t] + ps[2][t] + ps[3][t];
        float mx = tot, sm = tot;
        #pragma unroll
        for (int o = 32; o > 0; o >>= 1) {
            mx = fmaxf(mx, __shfl_down(mx, o));
            sm += __shfl_down(sm, o);
        }
        if (t == 0) {
            float avg = sm / (float)NEXP;
            out[2 * NTOK * TOPK] = (mx - avg) / (avg + 1e-5f);
        }
    }
}

// ============================================================================
// Fallback for tiny workspace: R1 fused fp32 kernel (known-correct).
// ============================================================================
__global__ __launch_bounds__(256) void fused_fallback_kernel(
    const float* __restrict__ x, const int* __restrict__ mask,
    const float* __restrict__ W, const float* __restrict__ gbias,
    const float* __restrict__ ebias, float* __restrict__ out,
    unsigned int* __restrict__ counts)
{
    __shared__ float As[64][36];
    __shared__ float Bs[64][36];
    __shared__ float Lg[64][NEXP + 1];
    __shared__ float s_gb[NEXP], s_eb[NEXP];
    __shared__ unsigned int s_cnt[NEXP];
    const int tid = threadIdx.x;
    const int tx = tid & 15, ty = tid >> 4;
    const int m0 = blockIdx.x * 64;
    if (tid < NEXP) { s_gb[tid] = gbias[tid]; s_eb[tid] = ebias[tid]; s_cnt[tid] = 0u; }
    float acc[4][4] = {};
    for (int kb = 0; kb < CDIM; kb += 32) {
        __syncthreads();
        #pragma unroll
        for (int p = 0; p < 2; p++) {
            int lin = tid + p * 256; int m = lin >> 3; int c4 = (lin & 7) << 2;
            *(float4*)&As[m][c4] = *(const float4*)&x[(size_t)(m0 + m) * CDIM + kb + c4];
            *(float4*)&Bs[m][c4] = *(const float4*)&W[(size_t)m * CDIM + kb + c4];
        }
        __syncthreads();
        #pragma unroll
        for (int k4 = 0; k4 < 32; k4 += 4) {
            float4 a[4], b[4];
            #pragma unroll
            for (int i = 0; i < 4; i++) a[i] = *(const float4*)&As[ty * 4 + i][k4];
            #pragma unroll
            for (int j = 0; j < 4; j++) b[j] = *(const float4*)&Bs[tx * 4 + j][k4];
            #pragma unroll
            for (int i = 0; i < 4; i++)
                #pragma unroll
                for (int j = 0; j < 4; j++)
                    acc[i][j] += a[i].x * b[j].x + a[i].y * b[j].y
                               + a[i].z * b[j].z + a[i].w * b[j].w;
        }
    }
    __syncthreads();
    #pragma unroll
    for (int i = 0; i < 4; i++)
        #pragma unroll
        for (int j = 0; j < 4; j++)
            Lg[ty * 4 + i][tx * 4 + j] = acc[i][j] + s_gb[tx * 4 + j];
    __syncthreads();
    if (tid < 64) {
        const int g = m0 + tid;
        unsigned long long used = 0ull;
        int idxs[TOPK]; float probs[TOPK]; float psum = 0.f;
        #pragma unroll
        for (int k = 0; k < TOPK; k++) {
            float best = -INFINITY; int bi = 0;
            for (int n = 0; n < NEXP; n++) {
                if ((used >> n) & 1ull) continue;
                float vv = Lg[tid][n] + s_eb[n];
                if (vv > best) { best = vv; bi = n; }
            }
            used |= (1ull << bi);
            idxs[k] = bi;
            float p = 1.f / (1.f + expf(-Lg[tid][bi]));
            probs[k] = p; psum += p;
        }
        float inv = 1.f / psum;
        #pragma unroll
        for (int k = 0; k < TOPK; k++) {
            out[(size_t)g * TOPK + k] = (float)idxs[k];
            out[(size_t)NTOK * TOPK + (size_t)g * TOPK + k] = probs[k] * inv;
        }
        if (mask[g] != 0)
            #pragma unroll
            for (int k = 0; k < TOPK; k++) atomicAdd(&s_cnt[idxs[k]], 1u);
    }
    __syncthreads();
    if (tid < NEXP && s_cnt[tid] != 0u) atomicAdd(&counts[tid], s_cnt[tid]);
}

__global__ void finalize_atomic_kernel(const unsigned int* __restrict__ counts,
                                       float* __restrict__ out)
{
    const int t = threadIdx.x;
    float c  = (float)counts[t];
    float mx = c, sm = c;
    #pragma unroll
    for (int o = 32; o > 0; o >>= 1) {
        mx = fmaxf(mx, __shfl_down(mx, o));
        sm += __shfl_down(sm, o);
    }
    if (t == 0) {
        float avg = sm / (float)NEXP;
        out[2 * NTOK * TOPK] = (mx - avg) / (avg + 1e-5f);
    }
}

extern "C" void kernel_launch(void* const* d_in, const int* in_sizes, int n_in,
                              void* d_out, int out_size, void* d_ws, size_t ws_size,
                              hipStream_t stream)
{
    const float* x     = (const float*)d_in[0];
    const int*   mask  = (const int*)  d_in[1];
    const float* W     = (const float*)d_in[2];
    const float* gbias = (const float*)d_in[3];
    const float* ebias = (const float*)d_in[4];
    float* out = (float*)d_out;

    // ws layout: [Wh 256KB][Wl 256KB][blockcnt 128KB]
    const size_t whB  = (size_t)NEXP * CDIM * sizeof(_Float16);   // 256 KB
    const size_t bcB  = (size_t)GBLK * NEXP * sizeof(float);      // 128 KB
    const size_t need = 2 * whB + bcB;

    if (ws_size >= need) {
        _Float16* Wh = (_Float16*)d_ws;
        _Float16* Wl = (_Float16*)((char*)d_ws + whB);
        float* blockcnt = (float*)((char*)d_ws + 2 * whB);

        pack_w16_kernel<<<64, 256, 0, stream>>>(W, Wh, Wl);
        gate_fused_kernel<<<GBLK, 512, 0, stream>>>(x, Wh, Wl, mask, gbias, ebias, out, blockcnt);
        finalize_kernel<<<1, 256, 0, stream>>>(blockcnt, out);
        return;
    }

    // Fallback: fused fp32 kernel + global-atomic counts
    unsigned int* counts = (unsigned int*)d_ws;
    hipMemsetAsync(d_ws, 0, NEXP * sizeof(unsigned int), stream);
    fused_fallback_kernel<<<NTOK / 64, 256, 0, stream>>>(x, mask, W, gbias, ebias, out, counts);
    finalize_atomic_kernel<<<1, 64, 0, stream>>>(counts, out);
}

// Round 8
// 225.395 us; speedup vs baseline: 1.0025x; 1.0025x over previous
//
#include <hip/hip_runtime.h>
#include <math.h>

// Problem constants (MoEGate: B=4,T=4096,C=2048,E=64,K=8)
#define NTOK   16384
#define CDIM   2048
#define NEXP   64
#define TOPK   8
#define TOKB   32            // tokens per block (2 MFMA row-tiles)
#define NWAVE  8             // waves per block (in-block k-split factor)
#define GBLK   (NTOK / TOKB) // 512 blocks
#define XPITCH 1040          // LDS row pitch (bytes): 1024 + 16 staggers banks

typedef _Float16 f16x8 __attribute__((ext_vector_type(8)));
typedef float    f32x4 __attribute__((ext_vector_type(4)));

// ============================================================================
// Kernel 1: pack W[64][2048] fp32 into f16 hi/lo images in MFMA B-fragment
// order. Entry t = ((s*4 + nt)*64 + lane): 8 f16 for (expert = nt*16+(lane&15),
// k = s*32 + (lane>>4)*8 + j). GEMM lane then loads one contiguous 16B chunk.
// ============================================================================
__global__ __launch_bounds__(256) void pack_w16_kernel(
    const float* __restrict__ W,
    _Float16* __restrict__ Wh, _Float16* __restrict__ Wl)
{
    int t    = blockIdx.x * 256 + threadIdx.x;   // 0..16383
    int lane = t & 63;
    int nt   = (t >> 6) & 3;
    int s    = t >> 8;                           // k32-step, 0..63
    int e    = nt * 16 + (lane & 15);
    int k    = s * 32 + (lane >> 4) * 8;
    const float* src = W + (size_t)e * CDIM + k;
    #pragma unroll
    for (int j = 0; j < 8; j++) {
        float x = src[j];
        _Float16 h = (_Float16)x;                // rte
        Wh[(size_t)t * 8 + j] = h;
        Wl[(size_t)t * 8 + j] = (_Float16)(x - (float)h);
    }
}

__device__ __forceinline__ void split_f16(
    const float4 v0, const float4 v1, f16x8& ah, f16x8& al)
{
    float xr[8] = {v0.x, v0.y, v0.z, v0.w, v1.x, v1.y, v1.z, v1.w};
    #pragma unroll
    for (int j = 0; j < 8; j++) {
        _Float16 h = (_Float16)xr[j];
        ah[j] = h;
        al[j] = (_Float16)(xr[j] - (float)h);    // exact residual
    }
}

// ============================================================================
// Kernel 2 (FUSED): DOUBLE-buffered reg-staged LDS streaming, ONE raw barrier
// per chunk, counted-vmcnt pipeline + 8-way k-split.
// R15: R14's single buffer needed 2 barriers/chunk and its staged loads got
// only the consume phase (~300cy) of flight before the next ds_write's vmcnt
// wait. Double buffer: write(c+2)->buf[c&1] is ordered after consume(c) by
// the single intervening barrier(c+1), so the read-protection barrier is
// gone. Issue order per phase: W(c) FIRST (oldest), then v(c+1) (newer),
// then ds_write v(c) [compiler: vmcnt(12) = waits only the P-set issued a
// full phase ago], lgkm0 + RAW s_barrier (publish; vmem stays in flight),
// then consume [MFMA waits vmcnt(4) = W only; v(c+1) flies on]. Staged
// loads now get a full phase (~500+cy) + 16 waves/CU TLP of latency cover.
// LDS: buf0/buf1 = 2 x 32 rows x 1040 B (bank-staggered, 2-way alias free);
// the dead 64-KB sacc OVERLAYS both buffers (66.8 KB total -> 2 blocks/CU,
// grid 512, (512,4) 128-reg cap; ~+16 regs for the 2nd staging set, est
// ~96 total, no spill). Post-loop __syncthreads() before sacc overlay write.
// Epilogue unchanged (verified): waves 0/1 reduce w-ascending + 16-lane
// shfl_xor top-8 (strict >, lowest index wins ties = JAX). ZERO global
// atomics.
// ============================================================================
__global__ __launch_bounds__(512, 4) void gate_fused_kernel(
    const float* __restrict__ x,       // [NTOK][CDIM]
    const _Float16* __restrict__ Wh,   // packed image, 256 KB (L2-hot)
    const _Float16* __restrict__ Wl,   // packed image, 256 KB (L2-hot)
    const int*   __restrict__ mask,    // [NTOK]
    const float* __restrict__ gbias,   // [NEXP]
    const float* __restrict__ ebias,   // [NEXP]
    float*       __restrict__ out,     // [2*NTOK*TOPK + 1]
    float*       __restrict__ blockcnt)// [GBLK][NEXP]
{
    __shared__ char smem[2 * 32 * XPITCH];   // 66560 B: buf0 | buf1
    __shared__ unsigned int cnt[NEXP];
    char* buf0 = smem;
    char* buf1 = smem + 32 * XPITCH;
    f32x4 (*sacc)[2][4][64] = (f32x4 (*)[2][4][64])smem;  // 64-KB overlay (post-loop)

    const int tid  = threadIdx.x;
    const int lane = tid & 63;
    const int wid  = tid >> 6;               // 0..7
    if (tid < NEXP) cnt[tid] = 0u;

    const int tok0 = blockIdx.x * TOKB;
    const int col  = lane & 15;              // token row for A / expert col for C
    const int q    = lane >> 4;              // quad
    const char* gx = (const char*)(x + (size_t)tok0 * CDIM);
    const f16x8* whp = (const f16x8*)Wh + lane;
    const f16x8* wlp = (const f16x8*)Wl + lane;

    f32x4 accA[4], accB[4];
    #pragma unroll
    for (int nt = 0; nt < 4; nt++) {
        accA[nt] = (f32x4){0.f, 0.f, 0.f, 0.f};
        accB[nt] = (f32x4){0.f, 0.f, 0.f, 0.f};
    }

    const int rowA = col, rowB = 16 + col;
    const unsigned offb = (unsigned)(wid * 128 + q * 32);

    // x-row loads for chunk cc into a 4-float4 register set (4 rows/wave)
    #define LOADX(d0, d1, d2, d3, cc) do {                                       \
        const char* gc_ = gx + (size_t)(cc) * 1024;                              \
        d0 = *(const float4*)(gc_ + (size_t)(wid * 4 + 0) * 8192 + lane * 16);   \
        d1 = *(const float4*)(gc_ + (size_t)(wid * 4 + 1) * 8192 + lane * 16);   \
        d2 = *(const float4*)(gc_ + (size_t)(wid * 4 + 2) * 8192 + lane * 16);   \
        d3 = *(const float4*)(gc_ + (size_t)(wid * 4 + 3) * 8192 + lane * 16);   \
    } while (0)

    #define WRITEX(BUF, s0, s1, s2, s3) do {                                     \
        *(float4*)((BUF) + (wid * 4 + 0) * XPITCH + lane * 16) = s0;             \
        *(float4*)((BUF) + (wid * 4 + 1) * XPITCH + lane * 16) = s1;             \
        *(float4*)((BUF) + (wid * 4 + 2) * XPITCH + lane * 16) = s2;             \
        *(float4*)((BUF) + (wid * 4 + 3) * XPITCH + lane * 16) = s3;             \
    } while (0)

    #define CONSUME(BUF, BH, BL) do {                                            \
        float4 a0 = *(const float4*)((BUF) + rowA * XPITCH + offb);              \
        float4 a1 = *(const float4*)((BUF) + rowA * XPITCH + offb + 16);         \
        float4 c0 = *(const float4*)((BUF) + rowB * XPITCH + offb);              \
        float4 c1 = *(const float4*)((BUF) + rowB * XPITCH + offb + 16);         \
        f16x8 ahA, alA, ahB, alB;                                                \
        split_f16(a0, a1, ahA, alA);                                             \
        split_f16(c0, c1, ahB, alB);                                             \
        _Pragma("unroll")                                                        \
        for (int nt = 0; nt < 4; nt++) {                                         \
            accA[nt] = __builtin_amdgcn_mfma_f32_16x16x32_f16(ahA, BH[nt], accA[nt], 0, 0, 0); \
            accA[nt] = __builtin_amdgcn_mfma_f32_16x16x32_f16(alA, BH[nt], accA[nt], 0, 0, 0); \
            accA[nt] = __builtin_amdgcn_mfma_f32_16x16x32_f16(ahA, BL[nt], accA[nt], 0, 0, 0); \
            accB[nt] = __builtin_amdgcn_mfma_f32_16x16x32_f16(ahB, BH[nt], accB[nt], 0, 0, 0); \
            accB[nt] = __builtin_amdgcn_mfma_f32_16x16x32_f16(alB, BH[nt], accB[nt], 0, 0, 0); \
            accB[nt] = __builtin_amdgcn_mfma_f32_16x16x32_f16(ahB, BL[nt], accB[nt], 0, 0, 0); \
        }                                                                        \
    } while (0)

    // prologue: P = chunk 0
    float4 p0, p1, p2, p3, q0, q1, q2, q3;
    LOADX(p0, p1, p2, p3, 0);

    #pragma unroll
    for (int c = 0; c < 8; c += 2) {
        // ===== even phase: chunk c, buf0, write P, stage Q=loads(c+1) =====
        const int S0 = c * 8 + wid;          // global k32-step (k-remap, verified)
        f16x8 bh0[4], bl0[4];
        #pragma unroll
        for (int nt = 0; nt < 4; nt++) {     // W(c): OLDEST vmem this phase
            bh0[nt] = whp[(size_t)S0 * 256 + nt * 64];
            bl0[nt] = wlp[(size_t)S0 * 256 + nt * 64];
        }
        __builtin_amdgcn_sched_barrier(0);   // keep W older than Q
        LOADX(q0, q1, q2, q3, c + 1);        // newer; in flight past barrier+consume
        __builtin_amdgcn_sched_barrier(0);
        WRITEX(buf0, p0, p1, p2, p3);        // compiler: waits only P's vmcnt
        asm volatile("s_waitcnt lgkmcnt(0)" ::: "memory");
        __builtin_amdgcn_s_barrier();        // publish buf0 (NO vmcnt drain)
        __builtin_amdgcn_sched_barrier(0);
        CONSUME(buf0, bh0, bl0);             // MFMA waits vmcnt(4)=W; Q flies on
        __builtin_amdgcn_sched_barrier(0);

        // ===== odd phase: chunk c+1, buf1, write Q, stage P=loads(c+2) =====
        const int S1 = (c + 1) * 8 + wid;
        f16x8 bh1[4], bl1[4];
        #pragma unroll
        for (int nt = 0; nt < 4; nt++) {
            bh1[nt] = whp[(size_t)S1 * 256 + nt * 64];
            bl1[nt] = wlp[(size_t)S1 * 256 + nt * 64];
        }
        __builtin_amdgcn_sched_barrier(0);
        if (c + 2 < 8) LOADX(p0, p1, p2, p3, c + 2);
        __builtin_amdgcn_sched_barrier(0);
        WRITEX(buf1, q0, q1, q2, q3);
        asm volatile("s_waitcnt lgkmcnt(0)" ::: "memory");
        __builtin_amdgcn_s_barrier();        // publish buf1
        __builtin_amdgcn_sched_barrier(0);
        CONSUME(buf1, bh1, bl1);
        __builtin_amdgcn_sched_barrier(0);
    }
    #undef LOADX
    #undef WRITEX
    #undef CONSUME

    __syncthreads();                         // all reads of buf0/buf1 done -> overlay safe

    #pragma unroll
    for (int nt = 0; nt < 4; nt++) {
        sacc[wid][0][nt][lane] = accA[nt];
        sacc[wid][1][nt][lane] = accB[nt];
    }
    __syncthreads();

    // ---- epilogue: wave 0 -> tokenset 0, wave 1 -> tokenset 1
    if (wid < 2) {
        const int ts = wid;
        f32x4 zv[4];
        #pragma unroll
        for (int nt = 0; nt < 4; nt++) {
            f32x4 s = sacc[0][ts][nt][lane];
            #pragma unroll
            for (int w = 1; w < NWAVE; w++) s += sacc[w][ts][nt][lane]; // k-order
            zv[nt] = s;
        }

        float gb[4], eb[4];
        #pragma unroll
        for (int nt = 0; nt < 4; nt++) {
            gb[nt] = gbias[nt * 16 + col];
            eb[nt] = ebias[nt * 16 + col];
        }

        #pragma unroll
        for (int r = 0; r < 4; r++) {
            const int t = tok0 + ts * 16 + q * 4 + r;   // C layout: row = q*4+reg
            float z[4], sel[4];
            #pragma unroll
            for (int nt = 0; nt < 4; nt++) {
                z[nt]   = zv[nt][r] + gb[nt];
                sel[nt] = z[nt] + eb[nt];
            }

            int idxs[TOPK]; float probs[TOPK]; float psum = 0.f;
            #pragma unroll
            for (int rr = 0; rr < TOPK; rr++) {
                float bv = -INFINITY, bz = 0.f; int bidx = 1 << 30;
                #pragma unroll
                for (int nt = 0; nt < 4; nt++)
                    if (sel[nt] > bv) { bv = sel[nt]; bz = z[nt]; bidx = nt * 16 + col; }
                #pragma unroll
                for (int m = 1; m < 16; m <<= 1) {   // xor<16 stays in 16-lane group
                    float ov = __shfl_xor(bv, m);
                    float oz = __shfl_xor(bz, m);
                    int   oi = __shfl_xor(bidx, m);
                    if (ov > bv || (ov == bv && oi < bidx)) { bv = ov; bz = oz; bidx = oi; }
                }
                idxs[rr] = bidx;
                float p = 1.f / (1.f + expf(-bz));
                probs[rr] = p; psum += p;
                if ((bidx & 15) == col) sel[bidx >> 4] = -INFINITY;   // mark used
            }
            float inv = 1.f / psum;
            if (col < TOPK) {
                out[(size_t)t * TOPK + col] = (float)idxs[col];
                out[(size_t)NTOK * TOPK + (size_t)t * TOPK + col] = probs[col] * inv;
                if (mask[t] != 0) atomicAdd(&cnt[idxs[col]], 1u);
            }
        }
    }
    __syncthreads();
    if (tid < NEXP)
        blockcnt[(size_t)blockIdx.x * NEXP + tid] = (float)cnt[tid];
}

// ============================================================================
// Kernel 3: tree-sum per-block counts -> maxvio. One block, 256 threads.
// ============================================================================
__global__ __launch_bounds__(256) void finalize_kernel(
    const float* __restrict__ blockcnt, float* __restrict__ out)
{
    __shared__ float ps[4][NEXP];
    const int t = threadIdx.x;
    const int e = t & 63, c = t >> 6;
    float s = 0.f;
    #pragma unroll 8
    for (int b = 0; b < GBLK / 4; b++)
        s += blockcnt[(size_t)(c * (GBLK / 4) + b) * NEXP + e];
    ps[c][e] = s;
    __syncthreads();
    if (t < 64) {
        float tot = ps[0][t] + ps[1][t] + ps[2][t] + ps[3][t];
        float mx = tot, sm = tot;
        #pragma unroll
        for (int o = 32; o > 0; o >>= 1) {
            mx = fmaxf(mx, __shfl_down(mx, o));
            sm += __shfl_down(sm, o);
        }
        if (t == 0) {
            float avg = sm / (float)NEXP;
            out[2 * NTOK * TOPK] = (mx - avg) / (avg + 1e-5f);
        }
    }
}

// ============================================================================
// Fallback for tiny workspace: R1 fused fp32 kernel (known-correct).
// ============================================================================
__global__ __launch_bounds__(256) void fused_fallback_kernel(
    const float* __restrict__ x, const int* __restrict__ mask,
    const float* __restrict__ W, const float* __restrict__ gbias,
    const float* __restrict__ ebias, float* __restrict__ out,
    unsigned int* __restrict__ counts)
{
    __shared__ float As[64][36];
    __shared__ float Bs[64][36];
    __shared__ float Lg[64][NEXP + 1];
    __shared__ float s_gb[NEXP], s_eb[NEXP];
    __shared__ unsigned int s_cnt[NEXP];
    const int tid = threadIdx.x;
    const int tx = tid & 15, ty = tid >> 4;
    const int m0 = blockIdx.x * 64;
    if (tid < NEXP) { s_gb[tid] = gbias[tid]; s_eb[tid] = ebias[tid]; s_cnt[tid] = 0u; }
    float acc[4][4] = {};
    for (int kb = 0; kb < CDIM; kb += 32) {
        __syncthreads();
        #pragma unroll
        for (int p = 0; p < 2; p++) {
            int lin = tid + p * 256; int m = lin >> 3; int c4 = (lin & 7) << 2;
            *(float4*)&As[m][c4] = *(const float4*)&x[(size_t)(m0 + m) * CDIM + kb + c4];
            *(float4*)&Bs[m][c4] = *(const float4*)&W[(size_t)m * CDIM + kb + c4];
        }
        __syncthreads();
        #pragma unroll
        for (int k4 = 0; k4 < 32; k4 += 4) {
            float4 a[4], b[4];
            #pragma unroll
            for (int i = 0; i < 4; i++) a[i] = *(const float4*)&As[ty * 4 + i][k4];
            #pragma unroll
            for (int j = 0; j < 4; j++) b[j] = *(const float4*)&Bs[tx * 4 + j][k4];
            #pragma unroll
            for (int i = 0; i < 4; i++)
                #pragma unroll
                for (int j = 0; j < 4; j++)
                    acc[i][j] += a[i].x * b[j].x + a[i].y * b[j].y
                               + a[i].z * b[j].z + a[i].w * b[j].w;
        }
    }
    __syncthreads();
    #pragma unroll
    for (int i = 0; i < 4; i++)
        #pragma unroll
        for (int j = 0; j < 4; j++)
            Lg[ty * 4 + i][tx * 4 + j] = acc[i][j] + s_gb[tx * 4 + j];
    __syncthreads();
    if (tid < 64) {
        const int g = m0 + tid;
        unsigned long long used = 0ull;
        int idxs[TOPK]; float probs[TOPK]; float psum = 0.f;
        #pragma unroll
        for (int k = 0; k < TOPK; k++) {
            float best = -INFINITY; int bi = 0;
            for (int n = 0; n < NEXP; n++) {
                if ((used >> n) & 1ull) continue;
                float vv = Lg[tid][n] + s_eb[n];
                if (vv > best) { best = vv; bi = n; }
            }
            used |= (1ull << bi);
            idxs[k] = bi;
            float p = 1.f / (1.f + expf(-Lg[tid][bi]));
            probs[k] = p; psum += p;
        }
        float inv = 1.f / psum;
        #pragma unroll
        for (int k = 0; k < TOPK; k++) {
            out[(size_t)g * TOPK + k] = (float)idxs[k];
            out[(size_t)NTOK * TOPK + (size_t)g * TOPK + k] = probs[k] * inv;
        }
        if (mask[g] != 0)
            #pragma unroll
            for (int k = 0; k < TOPK; k++) atomicAdd(&s_cnt[idxs[k]], 1u);
    }
    __syncthreads();
    if (tid < NEXP && s_cnt[tid] != 0u) atomicAdd(&counts[tid], s_cnt[tid]);
}

__global__ void finalize_atomic_kernel(const unsigned int* __restrict__ counts,
                                       float* __restrict__ out)
{
    const int t = threadIdx.x;
    float c  = (float)counts[t];
    float mx = c, sm = c;
    #pragma unroll
    for (int o = 32; o > 0; o >>= 1) {
        mx = fmaxf(mx, __shfl_down(mx, o));
        sm += __shfl_down(sm, o);
    }
    if (t == 0) {
        float avg = sm / (float)NEXP;
        out[2 * NTOK * TOPK] = (mx - avg) / (avg + 1e-5f);
    }
}

extern "C" void kernel_launch(void* const* d_in, const int* in_sizes, int n_in,
                              void* d_out, int out_size, void* d_ws, size_t ws_size,
                              hipStream_t stream)
{
    const float* x     = (const float*)d_in[0];
    const int*   mask  = (const int*)  d_in[1];
    const float* W     = (const float*)d_in[2];
    const float* gbias = (const float*)d_in[3];
    const float* ebias = (const float*)d_in[4];
    float* out = (float*)d_out;

    // ws layout: [Wh 256KB][Wl 256KB][blockcnt 128KB]
    const size_t whB  = (size_t)NEXP * CDIM * sizeof(_Float16);   // 256 KB
    const size_t bcB  = (size_t)GBLK * NEXP * sizeof(float);      // 128 KB
    const size_t need = 2 * whB + bcB;

    if (ws_size >= need) {
        _Float16* Wh = (_Float16*)d_ws;
        _Float16* Wl = (_Float16*)((char*)d_ws + whB);
        float* blockcnt = (float*)((char*)d_ws + 2 * whB);

        pack_w16_kernel<<<64, 256, 0, stream>>>(W, Wh, Wl);
        gate_fused_kernel<<<GBLK, 512, 0, stream>>>(x, Wh, Wl, mask, gbias, ebias, out, blockcnt);
        finalize_kernel<<<1, 256, 0, stream>>>(blockcnt, out);
        return;
    }

    // Fallback: fused fp32 kernel + global-atomic counts
    unsigned int* counts = (unsigned int*)d_ws;
    hipMemsetAsync(d_ws, 0, NEXP * sizeof(unsigned int), stream);
    fused_fallback_kernel<<<NTOK / 64, 256, 0, stream>>>(x, mask, W, gbias, ebias, out, counts);
    finalize_atomic_kernel<<<1, 64, 0, stream>>>(counts, out);
}